// Round 5
// baseline (356.938 us; speedup 1.0000x reference)
//
#include <hip/hip_runtime.h>

#define N_NODES 100000
#define N_EDGES 1600000
#define SCAN_BS 1024
#define BSHIFT 5
#define NBUCK 3125   // N_NODES >> BSHIFT, exact: 3125*32 == 100000

static inline int cdiv(int a, int b) { return (a + b - 1) / b; }

__device__ inline float4 f4add(float4 a, float4 b) {
    a.x += b.x; a.y += b.y; a.z += b.z; a.w += b.w; return a;
}
__device__ inline float4 f4fma(float s, float4 w, float4 a) {
    a.x = fmaf(s, w.x, a.x); a.y = fmaf(s, w.y, a.y);
    a.z = fmaf(s, w.z, a.z); a.w = fmaf(s, w.w, a.w); return a;
}
// relu(di*a + b)
__device__ inline float4 f4relu(float di, float4 a, float4 b) {
    float4 o;
    o.x = fmaxf(fmaf(di, a.x, b.x), 0.0f);
    o.y = fmaxf(fmaf(di, a.y, b.y), 0.0f);
    o.z = fmaxf(fmaf(di, a.z, b.z), 0.0f);
    o.w = fmaxf(fmaf(di, a.w, b.w), 0.0f);
    return o;
}

// ---------------- CSR build ----------------

__global__ void k_zero_int(int* __restrict__ p, int n) {
    int i = blockIdx.x * blockDim.x + threadIdx.x;
    if (i < n) p[i] = 0;
}

// node in-degree histogram, 4 edges per thread
__global__ void k_hist(const int* __restrict__ dst, int* __restrict__ hist, int e4) {
    int i = blockIdx.x * blockDim.x + threadIdx.x;
    if (i >= e4) return;
    int4 d = ((const int4*)dst)[i];
    atomicAdd(&hist[d.x], 1);
    atomicAdd(&hist[d.y], 1);
    atomicAdd(&hist[d.z], 1);
    atomicAdd(&hist[d.w], 1);
}

// dinv[i] = rsqrt(deg+1); xd[i] = {x[i,:3]*dinv, 0}
__global__ void k_dinv_xd(const int* __restrict__ hist, const float* __restrict__ x,
                          float* __restrict__ dinv, float4* __restrict__ xd, int n) {
    int i = blockIdx.x * blockDim.x + threadIdx.x;
    if (i >= n) return;
    float di = rsqrtf((float)(hist[i] + 1));
    dinv[i] = di;
    float4 v;
    v.x = x[3 * i] * di; v.y = x[3 * i + 1] * di; v.z = x[3 * i + 2] * di; v.w = 0.0f;
    xd[i] = v;
}

__global__ void k_scan_block(const int* __restrict__ hist, int* __restrict__ rowptr,
                             int* __restrict__ sums, int n) {
    __shared__ int tmp[SCAN_BS];
    int t = threadIdx.x, b = blockIdx.x;
    int i = b * SCAN_BS + t;
    int v = (i < n) ? hist[i] : 0;
    tmp[t] = v;
    __syncthreads();
    for (int off = 1; off < SCAN_BS; off <<= 1) {
        int x = (t >= off) ? tmp[t - off] : 0;
        __syncthreads();
        tmp[t] += x;
        __syncthreads();
    }
    if (i <= n) rowptr[i] = tmp[t] - v;
    if (t == SCAN_BS - 1) sums[b] = tmp[t];
}

__global__ void k_scan_sums(int* __restrict__ sums, int nb) {
    __shared__ int tmp[128];
    int t = threadIdx.x;
    int v = (t < nb) ? sums[t] : 0;
    tmp[t] = v;
    __syncthreads();
    for (int off = 1; off < 128; off <<= 1) {
        int x = (t >= off) ? tmp[t - off] : 0;
        __syncthreads();
        tmp[t] += x;
        __syncthreads();
    }
    if (t < nb) sums[t] = tmp[t] - v;
}

__global__ void k_scan_add(int* __restrict__ rowptr, const int* __restrict__ sums,
                           int* __restrict__ cursor, int n) {
    int i = blockIdx.x * blockDim.x + threadIdx.x;
    if (i <= n) {
        int v = rowptr[i] + sums[i >> 10];
        rowptr[i] = v;
        if (i < n) cursor[i] = v;
    }
}

// bucket cursors: bcur[b] = rowptr[b<<BSHIFT]
__global__ void k_bcur(const int* __restrict__ rowptr, int* __restrict__ bcur) {
    int b = blockIdx.x * blockDim.x + threadIdx.x;
    if (b < NBUCK) bcur[b] = rowptr[b << BSHIFT];
}

// pass A: bin edges by dst bucket; packed = (dst&31)<<17 | src  (22 bits)
__global__ void k_binA(const int* __restrict__ src, const int* __restrict__ dst,
                       int* __restrict__ bcur, unsigned* __restrict__ tmp, int e4) {
    int i = blockIdx.x * blockDim.x + threadIdx.x;
    if (i >= e4) return;
    int4 s = ((const int4*)src)[i];
    int4 d = ((const int4*)dst)[i];
    int p;
    p = atomicAdd(&bcur[d.x >> BSHIFT], 1); tmp[p] = ((unsigned)(d.x & 31) << 17) | (unsigned)s.x;
    p = atomicAdd(&bcur[d.y >> BSHIFT], 1); tmp[p] = ((unsigned)(d.y & 31) << 17) | (unsigned)s.y;
    p = atomicAdd(&bcur[d.z >> BSHIFT], 1); tmp[p] = ((unsigned)(d.z & 31) << 17) | (unsigned)s.z;
    p = atomicAdd(&bcur[d.w >> BSHIFT], 1); tmp[p] = ((unsigned)(d.w & 31) << 17) | (unsigned)s.w;
}

// pass B: one workgroup per bucket; scatter within the bucket's small output window
__global__ __launch_bounds__(256) void k_fillb(const unsigned* __restrict__ tmp,
                                               const int* __restrict__ rowptr,
                                               int* __restrict__ cursor,
                                               int* __restrict__ srcs) {
    int b = blockIdx.x;
    int base = b << BSHIFT;
    int start = rowptr[base];
    int hi = (b + 1) << BSHIFT; if (hi > N_NODES) hi = N_NODES;
    int end = rowptr[hi];
    for (int k = start + threadIdx.x; k < end; k += 256) {
        unsigned p = tmp[k];
        int s = (int)(p & 0x1FFFFu);
        int d = base + (int)(p >> 17);
        int pos = atomicAdd(&cursor[d], 1);
        srcs[pos] = s;
    }
}

// ---------------- fused layer kernels ----------------

// layer 1 aggregate-first (4ch) + transform 3->32 + relu + transform 32->16, write h2n*dinv
__global__ __launch_bounds__(256) void g1k12(const int* __restrict__ rowptr,
                                             const int* __restrict__ srcs,
                                             const float4* __restrict__ xd,
                                             const float* __restrict__ dinv,
                                             const float* __restrict__ b1,
                                             const float* __restrict__ W1,
                                             const float* __restrict__ W2,
                                             float4* __restrict__ h2n, int n) {
    __shared__ float4 sW1[24];    // [3][32] as 3 rows x 8 quads
    __shared__ float4 sW2[128];   // [32][16] as 32 rows x 4 quads
    int t = threadIdx.x;
    if (t < 24) sW1[t] = ((const float4*)W1)[t];
    int u = t - 24;
    if (u >= 0 && u < 128) sW2[u] = ((const float4*)W2)[u];
    __syncthreads();
    int i = blockIdx.x * blockDim.x + t;
    if (i >= n) return;

    float4 acc = xd[i];                       // self loop
    int r0 = rowptr[i], r1 = rowptr[i + 1];
    for (int j = r0; j < r1; ++j) acc = f4add(acc, xd[srcs[j]]);

    float di = dinv[i];
    const float4* b14 = (const float4*)b1;
    float h[32];
#pragma unroll
    for (int q = 0; q < 8; ++q) {
        float4 s = {0, 0, 0, 0};
        s = f4fma(acc.x, sW1[q], s);
        s = f4fma(acc.y, sW1[8 + q], s);
        s = f4fma(acc.z, sW1[16 + q], s);
        float4 hv = f4relu(di, s, b14[q]);
        h[4 * q] = hv.x; h[4 * q + 1] = hv.y; h[4 * q + 2] = hv.z; h[4 * q + 3] = hv.w;
    }
    float4 o[4] = {{0,0,0,0},{0,0,0,0},{0,0,0,0},{0,0,0,0}};
#pragma unroll
    for (int k = 0; k < 32; ++k) {
        float hk = h[k];
#pragma unroll
        for (int q = 0; q < 4; ++q) o[q] = f4fma(hk, sW2[k * 4 + q], o[q]);
    }
#pragma unroll
    for (int q = 0; q < 4; ++q) {
        o[q].x *= di; o[q].y *= di; o[q].z *= di; o[q].w *= di;
        h2n[(size_t)i * 4 + q] = o[q];
    }
}

// layer 2 gather (16ch) + relu + transform 16->8, write h3n*dinv
__global__ __launch_bounds__(256) void g2(const int* __restrict__ rowptr,
                                          const int* __restrict__ srcs,
                                          const float4* __restrict__ h2n,
                                          const float* __restrict__ dinv,
                                          const float* __restrict__ b2,
                                          const float* __restrict__ W3,
                                          float4* __restrict__ h3n, int n) {
    __shared__ float4 sW3[32];    // [16][8] as 16 rows x 2 quads
    int t = threadIdx.x;
    if (t < 32) sW3[t] = ((const float4*)W3)[t];
    __syncthreads();
    int i = blockIdx.x * blockDim.x + t;
    if (i >= n) return;

    float4 a[4];
#pragma unroll
    for (int q = 0; q < 4; ++q) a[q] = h2n[(size_t)i * 4 + q];   // self loop
    int r0 = rowptr[i], r1 = rowptr[i + 1];
    for (int j = r0; j < r1; ++j) {
        int s = srcs[j];
#pragma unroll
        for (int q = 0; q < 4; ++q) a[q] = f4add(a[q], h2n[(size_t)s * 4 + q]);
    }
    float di = dinv[i];
    const float4* b24 = (const float4*)b2;
    float act[16];
#pragma unroll
    for (int q = 0; q < 4; ++q) {
        float4 v = f4relu(di, a[q], b24[q]);
        act[4 * q] = v.x; act[4 * q + 1] = v.y; act[4 * q + 2] = v.z; act[4 * q + 3] = v.w;
    }
    float4 o0 = {0,0,0,0}, o1 = {0,0,0,0};
#pragma unroll
    for (int k = 0; k < 16; ++k) {
        o0 = f4fma(act[k], sW3[k * 2], o0);
        o1 = f4fma(act[k], sW3[k * 2 + 1], o1);
    }
    o0.x *= di; o0.y *= di; o0.z *= di; o0.w *= di;
    o1.x *= di; o1.y *= di; o1.z *= di; o1.w *= di;
    h3n[(size_t)i * 2]     = o0;
    h3n[(size_t)i * 2 + 1] = o1;
}

// layer 3 gather (8ch) + relu + final 8->1 linear
__global__ __launch_bounds__(256) void g3(const int* __restrict__ rowptr,
                                          const int* __restrict__ srcs,
                                          const float4* __restrict__ h3n,
                                          const float* __restrict__ dinv,
                                          const float* __restrict__ b3,
                                          const float* __restrict__ Wf,
                                          const float* __restrict__ bf,
                                          float* __restrict__ out, int n) {
    int i = blockIdx.x * blockDim.x + threadIdx.x;
    if (i >= n) return;
    float4 a0 = h3n[(size_t)i * 2];
    float4 a1 = h3n[(size_t)i * 2 + 1];
    int r0 = rowptr[i], r1 = rowptr[i + 1];
    for (int j = r0; j < r1; ++j) {
        int s = srcs[j];
        a0 = f4add(a0, h3n[(size_t)s * 2]);
        a1 = f4add(a1, h3n[(size_t)s * 2 + 1]);
    }
    float di = dinv[i];
    float4 bb0 = ((const float4*)b3)[0], bb1 = ((const float4*)b3)[1];
    float4 w0 = ((const float4*)Wf)[0],  w1 = ((const float4*)Wf)[1];
    float4 r0v = f4relu(di, a0, bb0);
    float4 r1v = f4relu(di, a1, bb1);
    float s = bf[0];
    s += r0v.x * w0.x + r0v.y * w0.y + r0v.z * w0.z + r0v.w * w0.w;
    s += r1v.x * w1.x + r1v.y * w1.y + r1v.z * w1.z + r1v.w * w1.w;
    out[i] = s;
}

// ---------------- launch ----------------

extern "C" void kernel_launch(void* const* d_in, const int* in_sizes, int n_in,
                              void* d_out, int out_size, void* d_ws, size_t ws_size,
                              hipStream_t stream) {
    const float* x  = (const float*)d_in[0];
    const int*   ei = (const int*)d_in[1];
    const float* W1 = (const float*)d_in[2];
    const float* b1 = (const float*)d_in[3];
    const float* W2 = (const float*)d_in[4];
    const float* b2 = (const float*)d_in[5];
    const float* W3 = (const float*)d_in[6];
    const float* b3 = (const float*)d_in[7];
    const float* Wf = (const float*)d_in[8];
    const float* bf = (const float*)d_in[9];
    float* out = (float*)d_out;

    const int n = N_NODES;
    const int e = N_EDGES;
    const int* src = ei;
    const int* dst = ei + e;

    // workspace: xd[n]f4 | h2n[n*4]f4 | h3n[n*2]f4 | dinv[n] | srcs[e] | tmp[e] |
    //            rowptr[n+1] | cursor[n] | hist[n] | sums[128] | bcur[NBUCK]
    float4*   xd   = (float4*)d_ws;
    float4*   h2n  = xd + n;
    float4*   h3n  = h2n + (size_t)n * 4;
    float*    dinv = (float*)(h3n + (size_t)n * 2);
    int*      srcs   = (int*)(dinv + n);
    unsigned* tmp    = (unsigned*)(srcs + e);
    int*      rowptr = (int*)(tmp + e);
    int*      cursor = rowptr + (n + 1);
    int*      hist   = cursor + n;
    int*      sums   = hist + n;
    int*      bcur   = sums + 128;

    const int B = 256;
    const int nScanBlocks = cdiv(n, SCAN_BS);   // 98
    const int e4 = e / 4;

    // ---- CSR build + dinv + xd ----
    k_zero_int<<<cdiv(n, B), B, 0, stream>>>(hist, n);
    k_hist<<<cdiv(e4, B), B, 0, stream>>>(dst, hist, e4);
    k_dinv_xd<<<cdiv(n, B), B, 0, stream>>>(hist, x, dinv, xd, n);
    k_scan_block<<<nScanBlocks, SCAN_BS, 0, stream>>>(hist, rowptr, sums, n);
    k_scan_sums<<<1, 128, 0, stream>>>(sums, nScanBlocks);
    k_scan_add<<<cdiv(n + 1, B), B, 0, stream>>>(rowptr, sums, cursor, n);
    k_bcur<<<cdiv(NBUCK, B), B, 0, stream>>>(rowptr, bcur);

    // ---- two-pass write-coherent counting sort ----
    k_binA<<<cdiv(e4, B), B, 0, stream>>>(src, dst, bcur, tmp, e4);
    k_fillb<<<NBUCK, B, 0, stream>>>(tmp, rowptr, cursor, srcs);

    // ---- fused layers ----
    g1k12<<<cdiv(n, B), B, 0, stream>>>(rowptr, srcs, xd, dinv, b1, W1, W2, h2n, n);
    g2<<<cdiv(n, B), B, 0, stream>>>(rowptr, srcs, h2n, dinv, b2, W3, h3n, n);
    g3<<<cdiv(n, B), B, 0, stream>>>(rowptr, srcs, h3n, dinv, b3, Wf, bf, out, n);
}

// Round 6
// 228.844 us; speedup vs baseline: 1.5597x; 1.5597x over previous
//
#include <hip/hip_runtime.h>

#define N_NODES 100000
#define N_EDGES 1600000
#define SCAN_BS 1024
#define NXCD 8
#define OWNER_DIV 12500   // N_NODES / NXCD: node i owned by XCD i/12500

static inline int cdiv(int a, int b) { return (a + b - 1) / b; }

__device__ inline float4 f4add(float4 a, float4 b) {
    a.x += b.x; a.y += b.y; a.z += b.z; a.w += b.w; return a;
}
__device__ inline float4 f4fma(float s, float4 w, float4 a) {
    a.x = fmaf(s, w.x, a.x); a.y = fmaf(s, w.y, a.y);
    a.z = fmaf(s, w.z, a.z); a.w = fmaf(s, w.w, a.w); return a;
}
// relu(di*a + b)
__device__ inline float4 f4relu(float di, float4 a, float4 b) {
    float4 o;
    o.x = fmaxf(fmaf(di, a.x, b.x), 0.0f);
    o.y = fmaxf(fmaf(di, a.y, b.y), 0.0f);
    o.z = fmaxf(fmaf(di, a.z, b.z), 0.0f);
    o.w = fmaxf(fmaf(di, a.w, b.w), 0.0f);
    return o;
}

// ---------------- CSR build ----------------

__global__ void k_zero_int(int* __restrict__ p, int n) {
    int i = blockIdx.x * blockDim.x + threadIdx.x;
    if (i < n) p[i] = 0;
}

// XCD-owner-filtered histogram: block role = blockIdx&7 handles only its node range.
// Grid covers the edge list 8x; L3 absorbs the re-reads, hist lines stay in one L2.
__global__ void k_hist(const int* __restrict__ dst, int* __restrict__ hist, int e4) {
    int role = blockIdx.x & (NXCD - 1);
    int i = (blockIdx.x >> 3) * blockDim.x + threadIdx.x;
    if (i >= e4) return;
    int4 d = ((const int4*)dst)[i];
    if (d.x / OWNER_DIV == role) atomicAdd(&hist[d.x], 1);
    if (d.y / OWNER_DIV == role) atomicAdd(&hist[d.y], 1);
    if (d.z / OWNER_DIV == role) atomicAdd(&hist[d.z], 1);
    if (d.w / OWNER_DIV == role) atomicAdd(&hist[d.w], 1);
}

// dinv[i] = rsqrt(deg+1); xd[i] = {x[i,:3]*dinv, 0}
__global__ void k_dinv_xd(const int* __restrict__ hist, const float* __restrict__ x,
                          float* __restrict__ dinv, float4* __restrict__ xd, int n) {
    int i = blockIdx.x * blockDim.x + threadIdx.x;
    if (i >= n) return;
    float di = rsqrtf((float)(hist[i] + 1));
    dinv[i] = di;
    float4 v;
    v.x = x[3 * i] * di; v.y = x[3 * i + 1] * di; v.z = x[3 * i + 2] * di; v.w = 0.0f;
    xd[i] = v;
}

__global__ void k_scan_block(const int* __restrict__ hist, int* __restrict__ rowptr,
                             int* __restrict__ sums, int n) {
    __shared__ int tmp[SCAN_BS];
    int t = threadIdx.x, b = blockIdx.x;
    int i = b * SCAN_BS + t;
    int v = (i < n) ? hist[i] : 0;
    tmp[t] = v;
    __syncthreads();
    for (int off = 1; off < SCAN_BS; off <<= 1) {
        int x = (t >= off) ? tmp[t - off] : 0;
        __syncthreads();
        tmp[t] += x;
        __syncthreads();
    }
    if (i <= n) rowptr[i] = tmp[t] - v;
    if (t == SCAN_BS - 1) sums[b] = tmp[t];
}

__global__ void k_scan_sums(int* __restrict__ sums, int nb) {
    __shared__ int tmp[128];
    int t = threadIdx.x;
    int v = (t < nb) ? sums[t] : 0;
    tmp[t] = v;
    __syncthreads();
    for (int off = 1; off < 128; off <<= 1) {
        int x = (t >= off) ? tmp[t - off] : 0;
        __syncthreads();
        tmp[t] += x;
        __syncthreads();
    }
    if (t < nb) sums[t] = tmp[t] - v;
}

__global__ void k_scan_add(int* __restrict__ rowptr, const int* __restrict__ sums,
                           int* __restrict__ cursor, int n) {
    int i = blockIdx.x * blockDim.x + threadIdx.x;
    if (i <= n) {
        int v = rowptr[i] + sums[i >> 10];
        rowptr[i] = v;
        if (i < n) cursor[i] = v;
    }
}

// XCD-owner-filtered counting-sort fill: writes to srcs land in the owner XCD's
// contiguous ~800KB window -> lines stay in that XCD's L2 and evict full.
__global__ void k_fill(const int* __restrict__ src, const int* __restrict__ dst,
                       int* __restrict__ cursor, int* __restrict__ srcs, int e4) {
    int role = blockIdx.x & (NXCD - 1);
    int i = (blockIdx.x >> 3) * blockDim.x + threadIdx.x;
    if (i >= e4) return;
    int4 s = ((const int4*)src)[i];
    int4 d = ((const int4*)dst)[i];
    if (d.x / OWNER_DIV == role) { int p = atomicAdd(&cursor[d.x], 1); srcs[p] = s.x; }
    if (d.y / OWNER_DIV == role) { int p = atomicAdd(&cursor[d.y], 1); srcs[p] = s.y; }
    if (d.z / OWNER_DIV == role) { int p = atomicAdd(&cursor[d.z], 1); srcs[p] = s.z; }
    if (d.w / OWNER_DIV == role) { int p = atomicAdd(&cursor[d.w], 1); srcs[p] = s.w; }
}

// ---------------- fused layer kernels ----------------

// layer 1 aggregate-first (4ch) + transform 3->32 + relu + transform 32->16, write h2n*dinv
__global__ __launch_bounds__(256) void g1k12(const int* __restrict__ rowptr,
                                             const int* __restrict__ srcs,
                                             const float4* __restrict__ xd,
                                             const float* __restrict__ dinv,
                                             const float* __restrict__ b1,
                                             const float* __restrict__ W1,
                                             const float* __restrict__ W2,
                                             float4* __restrict__ h2n, int n) {
    __shared__ float4 sW1[24];    // [3][32] as 3 rows x 8 quads
    __shared__ float4 sW2[128];   // [32][16] as 32 rows x 4 quads
    int t = threadIdx.x;
    if (t < 24) sW1[t] = ((const float4*)W1)[t];
    int u = t - 24;
    if (u >= 0 && u < 128) sW2[u] = ((const float4*)W2)[u];
    __syncthreads();
    int i = blockIdx.x * blockDim.x + t;
    if (i >= n) return;

    float4 acc = xd[i];                       // self loop
    int r0 = rowptr[i], r1 = rowptr[i + 1];
    for (int j = r0; j < r1; ++j) acc = f4add(acc, xd[srcs[j]]);

    float di = dinv[i];
    const float4* b14 = (const float4*)b1;
    float h[32];
#pragma unroll
    for (int q = 0; q < 8; ++q) {
        float4 s = {0, 0, 0, 0};
        s = f4fma(acc.x, sW1[q], s);
        s = f4fma(acc.y, sW1[8 + q], s);
        s = f4fma(acc.z, sW1[16 + q], s);
        float4 hv = f4relu(di, s, b14[q]);
        h[4 * q] = hv.x; h[4 * q + 1] = hv.y; h[4 * q + 2] = hv.z; h[4 * q + 3] = hv.w;
    }
    float4 o[4] = {{0,0,0,0},{0,0,0,0},{0,0,0,0},{0,0,0,0}};
#pragma unroll
    for (int k = 0; k < 32; ++k) {
        float hk = h[k];
#pragma unroll
        for (int q = 0; q < 4; ++q) o[q] = f4fma(hk, sW2[k * 4 + q], o[q]);
    }
#pragma unroll
    for (int q = 0; q < 4; ++q) {
        o[q].x *= di; o[q].y *= di; o[q].z *= di; o[q].w *= di;
        h2n[(size_t)i * 4 + q] = o[q];
    }
}

// layer 2 gather (16ch) + relu + transform 16->8, write h3n*dinv
__global__ __launch_bounds__(256) void g2(const int* __restrict__ rowptr,
                                          const int* __restrict__ srcs,
                                          const float4* __restrict__ h2n,
                                          const float* __restrict__ dinv,
                                          const float* __restrict__ b2,
                                          const float* __restrict__ W3,
                                          float4* __restrict__ h3n, int n) {
    __shared__ float4 sW3[32];    // [16][8] as 16 rows x 2 quads
    int t = threadIdx.x;
    if (t < 32) sW3[t] = ((const float4*)W3)[t];
    __syncthreads();
    int i = blockIdx.x * blockDim.x + t;
    if (i >= n) return;

    float4 a[4];
#pragma unroll
    for (int q = 0; q < 4; ++q) a[q] = h2n[(size_t)i * 4 + q];   // self loop
    int r0 = rowptr[i], r1 = rowptr[i + 1];
    for (int j = r0; j < r1; ++j) {
        int s = srcs[j];
#pragma unroll
        for (int q = 0; q < 4; ++q) a[q] = f4add(a[q], h2n[(size_t)s * 4 + q]);
    }
    float di = dinv[i];
    const float4* b24 = (const float4*)b2;
    float act[16];
#pragma unroll
    for (int q = 0; q < 4; ++q) {
        float4 v = f4relu(di, a[q], b24[q]);
        act[4 * q] = v.x; act[4 * q + 1] = v.y; act[4 * q + 2] = v.z; act[4 * q + 3] = v.w;
    }
    float4 o0 = {0,0,0,0}, o1 = {0,0,0,0};
#pragma unroll
    for (int k = 0; k < 16; ++k) {
        o0 = f4fma(act[k], sW3[k * 2], o0);
        o1 = f4fma(act[k], sW3[k * 2 + 1], o1);
    }
    o0.x *= di; o0.y *= di; o0.z *= di; o0.w *= di;
    o1.x *= di; o1.y *= di; o1.z *= di; o1.w *= di;
    h3n[(size_t)i * 2]     = o0;
    h3n[(size_t)i * 2 + 1] = o1;
}

// layer 3 gather (8ch) + relu + final 8->1 linear
__global__ __launch_bounds__(256) void g3(const int* __restrict__ rowptr,
                                          const int* __restrict__ srcs,
                                          const float4* __restrict__ h3n,
                                          const float* __restrict__ dinv,
                                          const float* __restrict__ b3,
                                          const float* __restrict__ Wf,
                                          const float* __restrict__ bf,
                                          float* __restrict__ out, int n) {
    int i = blockIdx.x * blockDim.x + threadIdx.x;
    if (i >= n) return;
    float4 a0 = h3n[(size_t)i * 2];
    float4 a1 = h3n[(size_t)i * 2 + 1];
    int r0 = rowptr[i], r1 = rowptr[i + 1];
    for (int j = r0; j < r1; ++j) {
        int s = srcs[j];
        a0 = f4add(a0, h3n[(size_t)s * 2]);
        a1 = f4add(a1, h3n[(size_t)s * 2 + 1]);
    }
    float di = dinv[i];
    float4 bb0 = ((const float4*)b3)[0], bb1 = ((const float4*)b3)[1];
    float4 w0 = ((const float4*)Wf)[0],  w1 = ((const float4*)Wf)[1];
    float4 r0v = f4relu(di, a0, bb0);
    float4 r1v = f4relu(di, a1, bb1);
    float s = bf[0];
    s += r0v.x * w0.x + r0v.y * w0.y + r0v.z * w0.z + r0v.w * w0.w;
    s += r1v.x * w1.x + r1v.y * w1.y + r1v.z * w1.z + r1v.w * w1.w;
    out[i] = s;
}

// ---------------- launch ----------------

extern "C" void kernel_launch(void* const* d_in, const int* in_sizes, int n_in,
                              void* d_out, int out_size, void* d_ws, size_t ws_size,
                              hipStream_t stream) {
    const float* x  = (const float*)d_in[0];
    const int*   ei = (const int*)d_in[1];
    const float* W1 = (const float*)d_in[2];
    const float* b1 = (const float*)d_in[3];
    const float* W2 = (const float*)d_in[4];
    const float* b2 = (const float*)d_in[5];
    const float* W3 = (const float*)d_in[6];
    const float* b3 = (const float*)d_in[7];
    const float* Wf = (const float*)d_in[8];
    const float* bf = (const float*)d_in[9];
    float* out = (float*)d_out;

    const int n = N_NODES;
    const int e = N_EDGES;
    const int* src = ei;
    const int* dst = ei + e;

    // workspace: xd[n]f4 | h2n[n*4]f4 | h3n[n*2]f4 | dinv[n] | srcs[e] |
    //            rowptr[n+1] | cursor[n] | hist[n] | sums[128]
    float4* xd   = (float4*)d_ws;
    float4* h2n  = xd + n;
    float4* h3n  = h2n + (size_t)n * 4;
    float*  dinv = (float*)(h3n + (size_t)n * 2);
    int*    srcs   = (int*)(dinv + n);
    int*    rowptr = srcs + e;
    int*    cursor = rowptr + (n + 1);
    int*    hist   = cursor + n;
    int*    sums   = hist + n;

    const int B = 256;
    const int nScanBlocks = cdiv(n, SCAN_BS);   // 98
    const int e4 = e / 4;                       // 400000, exact
    const int nSlice = cdiv(e4, B);             // 1563

    // ---- CSR build + dinv + xd ----
    k_zero_int<<<cdiv(n, B), B, 0, stream>>>(hist, n);
    k_hist<<<nSlice * NXCD, B, 0, stream>>>(dst, hist, e4);
    k_dinv_xd<<<cdiv(n, B), B, 0, stream>>>(hist, x, dinv, xd, n);
    k_scan_block<<<nScanBlocks, SCAN_BS, 0, stream>>>(hist, rowptr, sums, n);
    k_scan_sums<<<1, 128, 0, stream>>>(sums, nScanBlocks);
    k_scan_add<<<cdiv(n + 1, B), B, 0, stream>>>(rowptr, sums, cursor, n);

    // ---- XCD-owner-filtered counting-sort fill ----
    k_fill<<<nSlice * NXCD, B, 0, stream>>>(src, dst, cursor, srcs, e4);

    // ---- fused layers ----
    g1k12<<<cdiv(n, B), B, 0, stream>>>(rowptr, srcs, xd, dinv, b1, W1, W2, h2n, n);
    g2<<<cdiv(n, B), B, 0, stream>>>(rowptr, srcs, h2n, dinv, b2, W3, h3n, n);
    g3<<<cdiv(n, B), B, 0, stream>>>(rowptr, srcs, h3n, dinv, b3, Wf, bf, out, n);
}

// Round 7
// 135.704 us; speedup vs baseline: 2.6303x; 1.6863x over previous
//
#include <hip/hip_runtime.h>

#define N_NODES 100000
#define N_EDGES 1600000
#define RSHIFT 9
#define RSIZE 512
#define NREG 196            // cdiv(100000, 512)
#define CH 2048             // edges per workgroup in count/place
#define NWG_E 782           // cdiv(N_EDGES, CH)

static inline int cdiv(int a, int b) { return (a + b - 1) / b; }

__device__ inline float4 f4add(float4 a, float4 b) {
    a.x += b.x; a.y += b.y; a.z += b.z; a.w += b.w; return a;
}
__device__ inline float4 f4fma(float s, float4 w, float4 a) {
    a.x = fmaf(s, w.x, a.x); a.y = fmaf(s, w.y, a.y);
    a.z = fmaf(s, w.z, a.z); a.w = fmaf(s, w.w, a.w); return a;
}
// relu(di*a + b)
__device__ inline float4 f4relu(float di, float4 a, float4 b) {
    float4 o;
    o.x = fmaxf(fmaf(di, a.x, b.x), 0.0f);
    o.y = fmaxf(fmaf(di, a.y, b.y), 0.0f);
    o.z = fmaxf(fmaf(di, a.z, b.z), 0.0f);
    o.w = fmaxf(fmaf(di, a.w, b.w), 0.0f);
    return o;
}

// ---------------- radix-partition CSR build ----------------

__global__ void k_zero_int(int* __restrict__ p, int n) {
    int i = blockIdx.x * blockDim.x + threadIdx.x;
    if (i < n) p[i] = 0;
}

// pass 1: per-wg LDS histogram over regions; reserve exclusive output ranges
__global__ __launch_bounds__(256) void k_count(const int* __restrict__ dst,
                                               int* __restrict__ regionCount,
                                               int* __restrict__ wgOff) {
    __shared__ int h[NREG];
    int wg = blockIdx.x;
    for (int t = threadIdx.x; t < NREG; t += 256) h[t] = 0;
    __syncthreads();
    int e0 = wg * CH;
    int e1 = e0 + CH; if (e1 > N_EDGES) e1 = N_EDGES;
    const int4* d4 = (const int4*)dst;
    for (int k = e0 / 4 + threadIdx.x; k < e1 / 4; k += 256) {
        int4 d = d4[k];
        atomicAdd(&h[d.x >> RSHIFT], 1);
        atomicAdd(&h[d.y >> RSHIFT], 1);
        atomicAdd(&h[d.z >> RSHIFT], 1);
        atomicAdd(&h[d.w >> RSHIFT], 1);
    }
    __syncthreads();
    for (int t = threadIdx.x; t < NREG; t += 256)
        wgOff[wg * NREG + t] = atomicAdd(&regionCount[t], h[t]);
}

// scan region counts -> region bases; also set rowptr[N]
__global__ void k_scan_reg(const int* __restrict__ regionCount,
                           int* __restrict__ regionBase, int* __restrict__ rowptr) {
    __shared__ int tmp[256];
    int t = threadIdx.x;
    int v = (t < NREG) ? regionCount[t] : 0;
    tmp[t] = v;
    __syncthreads();
    for (int off = 1; off < 256; off <<= 1) {
        int x = (t >= off) ? tmp[t - off] : 0;
        __syncthreads();
        tmp[t] += x;
        __syncthreads();
    }
    if (t < NREG) regionBase[t] = tmp[t] - v;
    if (t == NREG - 1) regionBase[NREG] = tmp[t];
    if (t == 0) rowptr[N_NODES] = N_EDGES;
}

// pass 2: place packed (dstlocal,src) into exclusive contiguous staging ranges
__global__ __launch_bounds__(256) void k_place(const int* __restrict__ src,
                                               const int* __restrict__ dst,
                                               const int* __restrict__ regionBase,
                                               const int* __restrict__ wgOff,
                                               unsigned* __restrict__ staging) {
    __shared__ int cur[NREG];
    int wg = blockIdx.x;
    for (int t = threadIdx.x; t < NREG; t += 256)
        cur[t] = regionBase[t] + wgOff[wg * NREG + t];
    __syncthreads();
    int e0 = wg * CH;
    int e1 = e0 + CH; if (e1 > N_EDGES) e1 = N_EDGES;
    const int4* s4 = (const int4*)src;
    const int4* d4 = (const int4*)dst;
    for (int k = e0 / 4 + threadIdx.x; k < e1 / 4; k += 256) {
        int4 s = s4[k];
        int4 d = d4[k];
        int p;
        p = atomicAdd(&cur[d.x >> RSHIFT], 1); staging[p] = ((unsigned)(d.x & (RSIZE - 1)) << 17) | (unsigned)s.x;
        p = atomicAdd(&cur[d.y >> RSHIFT], 1); staging[p] = ((unsigned)(d.y & (RSIZE - 1)) << 17) | (unsigned)s.y;
        p = atomicAdd(&cur[d.z >> RSHIFT], 1); staging[p] = ((unsigned)(d.z & (RSIZE - 1)) << 17) | (unsigned)s.z;
        p = atomicAdd(&cur[d.w >> RSHIFT], 1); staging[p] = ((unsigned)(d.w & (RSIZE - 1)) << 17) | (unsigned)s.w;
    }
}

// pass 3: one wg per region -> local hist, scan, rowptr/dinv/xd, place srcs
__global__ __launch_bounds__(512) void k_build(const unsigned* __restrict__ staging,
                                               const int* __restrict__ regionBase,
                                               const float* __restrict__ x,
                                               int* __restrict__ rowptr,
                                               float* __restrict__ dinv,
                                               float4* __restrict__ xd,
                                               int* __restrict__ srcs) {
    __shared__ int cnt[RSIZE];
    __shared__ int scn[RSIZE];
    int r = blockIdx.x;
    int t = threadIdx.x;
    int base = r << RSHIFT;
    int nloc = N_NODES - base; if (nloc > RSIZE) nloc = RSIZE;
    int e0 = regionBase[r], e1 = regionBase[r + 1];
    cnt[t] = 0;
    __syncthreads();
    for (int k = e0 + t; k < e1; k += 512) atomicAdd(&cnt[staging[k] >> 17], 1);
    __syncthreads();
    int v = cnt[t];
    scn[t] = v;
    __syncthreads();
    for (int off = 1; off < RSIZE; off <<= 1) {
        int y = (t >= off) ? scn[t - off] : 0;
        __syncthreads();
        scn[t] += y;
        __syncthreads();
    }
    int excl = scn[t] - v;
    if (t < nloc) {
        int i = base + t;
        rowptr[i] = e0 + excl;
        float di = rsqrtf((float)(v + 1));
        dinv[i] = di;
        float4 vv;
        vv.x = x[3 * i] * di; vv.y = x[3 * i + 1] * di; vv.z = x[3 * i + 2] * di; vv.w = 0.0f;
        xd[i] = vv;
    }
    cnt[t] = e0 + excl;   // reuse as cursor
    __syncthreads();
    for (int k = e0 + t; k < e1; k += 512) {
        unsigned p = staging[k];
        int pos = atomicAdd(&cnt[p >> 17], 1);
        srcs[pos] = (int)(p & 0x1FFFFu);
    }
}

// ---------------- fused layer kernels ----------------

// layer 1 aggregate-first (4ch) + transform 3->32 + relu + transform 32->16, write h2n*dinv
__global__ __launch_bounds__(256) void g1k12(const int* __restrict__ rowptr,
                                             const int* __restrict__ srcs,
                                             const float4* __restrict__ xd,
                                             const float* __restrict__ dinv,
                                             const float* __restrict__ b1,
                                             const float* __restrict__ W1,
                                             const float* __restrict__ W2,
                                             float4* __restrict__ h2n, int n) {
    __shared__ float4 sW1[24];    // [3][32] as 3 rows x 8 quads
    __shared__ float4 sW2[128];   // [32][16] as 32 rows x 4 quads
    int t = threadIdx.x;
    if (t < 24) sW1[t] = ((const float4*)W1)[t];
    int u = t - 24;
    if (u >= 0 && u < 128) sW2[u] = ((const float4*)W2)[u];
    __syncthreads();
    int i = blockIdx.x * blockDim.x + t;
    if (i >= n) return;

    float4 acc = xd[i];                       // self loop
    int r0 = rowptr[i], r1 = rowptr[i + 1];
    for (int j = r0; j < r1; ++j) acc = f4add(acc, xd[srcs[j]]);

    float di = dinv[i];
    const float4* b14 = (const float4*)b1;
    float h[32];
#pragma unroll
    for (int q = 0; q < 8; ++q) {
        float4 s = {0, 0, 0, 0};
        s = f4fma(acc.x, sW1[q], s);
        s = f4fma(acc.y, sW1[8 + q], s);
        s = f4fma(acc.z, sW1[16 + q], s);
        float4 hv = f4relu(di, s, b14[q]);
        h[4 * q] = hv.x; h[4 * q + 1] = hv.y; h[4 * q + 2] = hv.z; h[4 * q + 3] = hv.w;
    }
    float4 o[4] = {{0,0,0,0},{0,0,0,0},{0,0,0,0},{0,0,0,0}};
#pragma unroll
    for (int k = 0; k < 32; ++k) {
        float hk = h[k];
#pragma unroll
        for (int q = 0; q < 4; ++q) o[q] = f4fma(hk, sW2[k * 4 + q], o[q]);
    }
#pragma unroll
    for (int q = 0; q < 4; ++q) {
        o[q].x *= di; o[q].y *= di; o[q].z *= di; o[q].w *= di;
        h2n[(size_t)i * 4 + q] = o[q];
    }
}

// layer 2 gather (16ch) + relu + transform 16->8, write h3n*dinv
__global__ __launch_bounds__(256) void g2(const int* __restrict__ rowptr,
                                          const int* __restrict__ srcs,
                                          const float4* __restrict__ h2n,
                                          const float* __restrict__ dinv,
                                          const float* __restrict__ b2,
                                          const float* __restrict__ W3,
                                          float4* __restrict__ h3n, int n) {
    __shared__ float4 sW3[32];    // [16][8] as 16 rows x 2 quads
    int t = threadIdx.x;
    if (t < 32) sW3[t] = ((const float4*)W3)[t];
    __syncthreads();
    int i = blockIdx.x * blockDim.x + t;
    if (i >= n) return;

    float4 a[4];
#pragma unroll
    for (int q = 0; q < 4; ++q) a[q] = h2n[(size_t)i * 4 + q];   // self loop
    int r0 = rowptr[i], r1 = rowptr[i + 1];
    for (int j = r0; j < r1; ++j) {
        int s = srcs[j];
#pragma unroll
        for (int q = 0; q < 4; ++q) a[q] = f4add(a[q], h2n[(size_t)s * 4 + q]);
    }
    float di = dinv[i];
    const float4* b24 = (const float4*)b2;
    float act[16];
#pragma unroll
    for (int q = 0; q < 4; ++q) {
        float4 v = f4relu(di, a[q], b24[q]);
        act[4 * q] = v.x; act[4 * q + 1] = v.y; act[4 * q + 2] = v.z; act[4 * q + 3] = v.w;
    }
    float4 o0 = {0,0,0,0}, o1 = {0,0,0,0};
#pragma unroll
    for (int k = 0; k < 16; ++k) {
        o0 = f4fma(act[k], sW3[k * 2], o0);
        o1 = f4fma(act[k], sW3[k * 2 + 1], o1);
    }
    o0.x *= di; o0.y *= di; o0.z *= di; o0.w *= di;
    o1.x *= di; o1.y *= di; o1.z *= di; o1.w *= di;
    h3n[(size_t)i * 2]     = o0;
    h3n[(size_t)i * 2 + 1] = o1;
}

// layer 3 gather (8ch) + relu + final 8->1 linear
__global__ __launch_bounds__(256) void g3(const int* __restrict__ rowptr,
                                          const int* __restrict__ srcs,
                                          const float4* __restrict__ h3n,
                                          const float* __restrict__ dinv,
                                          const float* __restrict__ b3,
                                          const float* __restrict__ Wf,
                                          const float* __restrict__ bf,
                                          float* __restrict__ out, int n) {
    int i = blockIdx.x * blockDim.x + threadIdx.x;
    if (i >= n) return;
    float4 a0 = h3n[(size_t)i * 2];
    float4 a1 = h3n[(size_t)i * 2 + 1];
    int r0 = rowptr[i], r1 = rowptr[i + 1];
    for (int j = r0; j < r1; ++j) {
        int s = srcs[j];
        a0 = f4add(a0, h3n[(size_t)s * 2]);
        a1 = f4add(a1, h3n[(size_t)s * 2 + 1]);
    }
    float di = dinv[i];
    float4 bb0 = ((const float4*)b3)[0], bb1 = ((const float4*)b3)[1];
    float4 w0 = ((const float4*)Wf)[0],  w1 = ((const float4*)Wf)[1];
    float4 r0v = f4relu(di, a0, bb0);
    float4 r1v = f4relu(di, a1, bb1);
    float s = bf[0];
    s += r0v.x * w0.x + r0v.y * w0.y + r0v.z * w0.z + r0v.w * w0.w;
    s += r1v.x * w1.x + r1v.y * w1.y + r1v.z * w1.z + r1v.w * w1.w;
    out[i] = s;
}

// ---------------- launch ----------------

extern "C" void kernel_launch(void* const* d_in, const int* in_sizes, int n_in,
                              void* d_out, int out_size, void* d_ws, size_t ws_size,
                              hipStream_t stream) {
    const float* x  = (const float*)d_in[0];
    const int*   ei = (const int*)d_in[1];
    const float* W1 = (const float*)d_in[2];
    const float* b1 = (const float*)d_in[3];
    const float* W2 = (const float*)d_in[4];
    const float* b2 = (const float*)d_in[5];
    const float* W3 = (const float*)d_in[6];
    const float* b3 = (const float*)d_in[7];
    const float* Wf = (const float*)d_in[8];
    const float* bf = (const float*)d_in[9];
    float* out = (float*)d_out;

    const int n = N_NODES;
    const int e = N_EDGES;
    const int* src = ei;
    const int* dst = ei + e;

    // workspace: xd[n]f4 | h2n[n*4]f4 | h3n[n*2]f4 | dinv[n] | srcs[e] | staging[e] |
    //            rowptr[n+1] | regionCount[NREG] | regionBase[NREG+1] | wgOff[NWG_E*NREG]
    float4*   xd   = (float4*)d_ws;
    float4*   h2n  = xd + n;
    float4*   h3n  = h2n + (size_t)n * 4;
    float*    dinv = (float*)(h3n + (size_t)n * 2);
    int*      srcs    = (int*)(dinv + n);
    unsigned* staging = (unsigned*)(srcs + e);
    int*      rowptr  = (int*)(staging + e);
    int*      regionCount = rowptr + (n + 1);
    int*      regionBase  = regionCount + NREG;
    int*      wgOff       = regionBase + (NREG + 1);

    const int B = 256;

    // ---- CSR build (radix partition) ----
    k_zero_int<<<cdiv(NREG, B), B, 0, stream>>>(regionCount, NREG);
    k_count<<<NWG_E, B, 0, stream>>>(dst, regionCount, wgOff);
    k_scan_reg<<<1, 256, 0, stream>>>(regionCount, regionBase, rowptr);
    k_place<<<NWG_E, B, 0, stream>>>(src, dst, regionBase, wgOff, staging);
    k_build<<<NREG, 512, 0, stream>>>(staging, regionBase, x, rowptr, dinv, xd, srcs);

    // ---- fused layers ----
    g1k12<<<cdiv(n, B), B, 0, stream>>>(rowptr, srcs, xd, dinv, b1, W1, W2, h2n, n);
    g2<<<cdiv(n, B), B, 0, stream>>>(rowptr, srcs, h2n, dinv, b2, W3, h3n, n);
    g3<<<cdiv(n, B), B, 0, stream>>>(rowptr, srcs, h3n, dinv, b3, Wf, bf, out, n);
}

// Round 8
// 126.626 us; speedup vs baseline: 2.8188x; 1.0717x over previous
//
#include <hip/hip_runtime.h>

#define N_NODES 100000
#define N_EDGES 1600000
#define RSHIFT 9
#define RSIZE 512
#define NREG 196            // cdiv(100000, 512)
#define CAP 16384           // staging slots per region (expected 8192, sd ~90)
#define CH 2048             // edges per workgroup in place pass
#define NWG_E 782           // cdiv(N_EDGES, CH)

static inline int cdiv(int a, int b) { return (a + b - 1) / b; }

__device__ inline float4 f4add(float4 a, float4 b) {
    a.x += b.x; a.y += b.y; a.z += b.z; a.w += b.w; return a;
}
__device__ inline float4 f4fma(float s, float4 w, float4 a) {
    a.x = fmaf(s, w.x, a.x); a.y = fmaf(s, w.y, a.y);
    a.z = fmaf(s, w.z, a.z); a.w = fmaf(s, w.w, a.w); return a;
}
// relu(di*a + b)
__device__ inline float4 f4relu(float di, float4 a, float4 b) {
    float4 o;
    o.x = fmaxf(fmaf(di, a.x, b.x), 0.0f);
    o.y = fmaxf(fmaf(di, a.y, b.y), 0.0f);
    o.z = fmaxf(fmaf(di, a.z, b.z), 0.0f);
    o.w = fmaxf(fmaf(di, a.w, b.w), 0.0f);
    return o;
}

// ---------------- CSR build: single-pass place + per-region build ----------------

__global__ void k_zero_cur(int* __restrict__ p) {
    int i = threadIdx.x;
    if (i < NREG) p[i] = 0;
}

// single pass: LDS hist chunk -> reserve window slice -> re-read chunk (L2-hot) and place
__global__ __launch_bounds__(256) void k_place(const int* __restrict__ src,
                                               const int* __restrict__ dst,
                                               int* __restrict__ regionCursor,
                                               unsigned* __restrict__ staging) {
    __shared__ int h[NREG];
    __shared__ int cur[NREG];
    int wg = blockIdx.x;
    for (int t = threadIdx.x; t < NREG; t += 256) h[t] = 0;
    __syncthreads();
    int e0 = wg * CH;
    int e1 = e0 + CH; if (e1 > N_EDGES) e1 = N_EDGES;
    const int4* s4 = (const int4*)src;
    const int4* d4 = (const int4*)dst;
    for (int k = e0 / 4 + threadIdx.x; k < e1 / 4; k += 256) {
        int4 d = d4[k];
        atomicAdd(&h[d.x >> RSHIFT], 1);
        atomicAdd(&h[d.y >> RSHIFT], 1);
        atomicAdd(&h[d.z >> RSHIFT], 1);
        atomicAdd(&h[d.w >> RSHIFT], 1);
    }
    __syncthreads();
    for (int t = threadIdx.x; t < NREG; t += 256)
        cur[t] = t * CAP + atomicAdd(&regionCursor[t], h[t]);
    __syncthreads();
    for (int k = e0 / 4 + threadIdx.x; k < e1 / 4; k += 256) {
        int4 s = s4[k];
        int4 d = d4[k];
        int p;
        p = atomicAdd(&cur[d.x >> RSHIFT], 1); staging[p] = ((unsigned)(d.x & (RSIZE - 1)) << 17) | (unsigned)s.x;
        p = atomicAdd(&cur[d.y >> RSHIFT], 1); staging[p] = ((unsigned)(d.y & (RSIZE - 1)) << 17) | (unsigned)s.y;
        p = atomicAdd(&cur[d.z >> RSHIFT], 1); staging[p] = ((unsigned)(d.z & (RSIZE - 1)) << 17) | (unsigned)s.z;
        p = atomicAdd(&cur[d.w >> RSHIFT], 1); staging[p] = ((unsigned)(d.w & (RSIZE - 1)) << 17) | (unsigned)s.w;
    }
}

// one wg per region: local hist, scan, rowptr/rowend/dinv/xd, place srcs into region window
__global__ __launch_bounds__(512) void k_build(const unsigned* __restrict__ staging,
                                               const int* __restrict__ regionCursor,
                                               const float* __restrict__ x,
                                               int* __restrict__ rowptr,
                                               int* __restrict__ rowend,
                                               float* __restrict__ dinv,
                                               float4* __restrict__ xd,
                                               int* __restrict__ srcs) {
    __shared__ int cnt[RSIZE];
    __shared__ int scn[RSIZE];
    int r = blockIdx.x;
    int t = threadIdx.x;
    int base = r << RSHIFT;
    int nloc = N_NODES - base; if (nloc > RSIZE) nloc = RSIZE;
    int e0 = r * CAP;
    int e1 = e0 + regionCursor[r];
    cnt[t] = 0;
    __syncthreads();
    for (int k = e0 + t; k < e1; k += 512) atomicAdd(&cnt[staging[k] >> 17], 1);
    __syncthreads();
    int v = cnt[t];
    scn[t] = v;
    __syncthreads();
    for (int off = 1; off < RSIZE; off <<= 1) {
        int y = (t >= off) ? scn[t - off] : 0;
        __syncthreads();
        scn[t] += y;
        __syncthreads();
    }
    int excl = scn[t] - v;
    if (t < nloc) {
        int i = base + t;
        rowptr[i] = e0 + excl;
        rowend[i] = e0 + excl + v;
        float di = rsqrtf((float)(v + 1));
        dinv[i] = di;
        float4 vv;
        vv.x = x[3 * i] * di; vv.y = x[3 * i + 1] * di; vv.z = x[3 * i + 2] * di; vv.w = 0.0f;
        xd[i] = vv;
    }
    cnt[t] = e0 + excl;   // reuse as cursor
    __syncthreads();
    for (int k = e0 + t; k < e1; k += 512) {
        unsigned p = staging[k];
        int pos = atomicAdd(&cnt[p >> 17], 1);
        srcs[pos] = (int)(p & 0x1FFFFu);
    }
}

// ---------------- fused layer kernels ----------------

// layer 1 aggregate-first (4ch) + transform 3->32 + relu + transform 32->16, write h2n*dinv
__global__ __launch_bounds__(256) void g1k12(const int* __restrict__ rowptr,
                                             const int* __restrict__ rowend,
                                             const int* __restrict__ srcs,
                                             const float4* __restrict__ xd,
                                             const float* __restrict__ dinv,
                                             const float* __restrict__ b1,
                                             const float* __restrict__ W1,
                                             const float* __restrict__ W2,
                                             float4* __restrict__ h2n, int n) {
    __shared__ float4 sW1[24];    // [3][32] as 3 rows x 8 quads
    __shared__ float4 sW2[128];   // [32][16] as 32 rows x 4 quads
    int t = threadIdx.x;
    if (t < 24) sW1[t] = ((const float4*)W1)[t];
    int u = t - 24;
    if (u >= 0 && u < 128) sW2[u] = ((const float4*)W2)[u];
    __syncthreads();
    int i = blockIdx.x * blockDim.x + t;
    if (i >= n) return;

    float4 acc = xd[i];                       // self loop
    int r0 = rowptr[i], r1 = rowend[i];
    for (int j = r0; j < r1; ++j) acc = f4add(acc, xd[srcs[j]]);

    float di = dinv[i];
    const float4* b14 = (const float4*)b1;
    float h[32];
#pragma unroll
    for (int q = 0; q < 8; ++q) {
        float4 s = {0, 0, 0, 0};
        s = f4fma(acc.x, sW1[q], s);
        s = f4fma(acc.y, sW1[8 + q], s);
        s = f4fma(acc.z, sW1[16 + q], s);
        float4 hv = f4relu(di, s, b14[q]);
        h[4 * q] = hv.x; h[4 * q + 1] = hv.y; h[4 * q + 2] = hv.z; h[4 * q + 3] = hv.w;
    }
    float4 o[4] = {{0,0,0,0},{0,0,0,0},{0,0,0,0},{0,0,0,0}};
#pragma unroll
    for (int k = 0; k < 32; ++k) {
        float hk = h[k];
#pragma unroll
        for (int q = 0; q < 4; ++q) o[q] = f4fma(hk, sW2[k * 4 + q], o[q]);
    }
#pragma unroll
    for (int q = 0; q < 4; ++q) {
        o[q].x *= di; o[q].y *= di; o[q].z *= di; o[q].w *= di;
        h2n[(size_t)i * 4 + q] = o[q];
    }
}

// layer 2 gather (16ch) + relu + transform 16->8, write h3n*dinv
__global__ __launch_bounds__(256) void g2(const int* __restrict__ rowptr,
                                          const int* __restrict__ rowend,
                                          const int* __restrict__ srcs,
                                          const float4* __restrict__ h2n,
                                          const float* __restrict__ dinv,
                                          const float* __restrict__ b2,
                                          const float* __restrict__ W3,
                                          float4* __restrict__ h3n, int n) {
    __shared__ float4 sW3[32];    // [16][8] as 16 rows x 2 quads
    int t = threadIdx.x;
    if (t < 32) sW3[t] = ((const float4*)W3)[t];
    __syncthreads();
    int i = blockIdx.x * blockDim.x + t;
    if (i >= n) return;

    float4 a[4];
#pragma unroll
    for (int q = 0; q < 4; ++q) a[q] = h2n[(size_t)i * 4 + q];   // self loop
    int r0 = rowptr[i], r1 = rowend[i];
    for (int j = r0; j < r1; ++j) {
        int s = srcs[j];
#pragma unroll
        for (int q = 0; q < 4; ++q) a[q] = f4add(a[q], h2n[(size_t)s * 4 + q]);
    }
    float di = dinv[i];
    const float4* b24 = (const float4*)b2;
    float act[16];
#pragma unroll
    for (int q = 0; q < 4; ++q) {
        float4 v = f4relu(di, a[q], b24[q]);
        act[4 * q] = v.x; act[4 * q + 1] = v.y; act[4 * q + 2] = v.z; act[4 * q + 3] = v.w;
    }
    float4 o0 = {0,0,0,0}, o1 = {0,0,0,0};
#pragma unroll
    for (int k = 0; k < 16; ++k) {
        o0 = f4fma(act[k], sW3[k * 2], o0);
        o1 = f4fma(act[k], sW3[k * 2 + 1], o1);
    }
    o0.x *= di; o0.y *= di; o0.z *= di; o0.w *= di;
    o1.x *= di; o1.y *= di; o1.z *= di; o1.w *= di;
    h3n[(size_t)i * 2]     = o0;
    h3n[(size_t)i * 2 + 1] = o1;
}

// layer 3 gather (8ch) + relu + final 8->1 linear
__global__ __launch_bounds__(256) void g3(const int* __restrict__ rowptr,
                                          const int* __restrict__ rowend,
                                          const int* __restrict__ srcs,
                                          const float4* __restrict__ h3n,
                                          const float* __restrict__ dinv,
                                          const float* __restrict__ b3,
                                          const float* __restrict__ Wf,
                                          const float* __restrict__ bf,
                                          float* __restrict__ out, int n) {
    int i = blockIdx.x * blockDim.x + threadIdx.x;
    if (i >= n) return;
    float4 a0 = h3n[(size_t)i * 2];
    float4 a1 = h3n[(size_t)i * 2 + 1];
    int r0 = rowptr[i], r1 = rowend[i];
    for (int j = r0; j < r1; ++j) {
        int s = srcs[j];
        a0 = f4add(a0, h3n[(size_t)s * 2]);
        a1 = f4add(a1, h3n[(size_t)s * 2 + 1]);
    }
    float di = dinv[i];
    float4 bb0 = ((const float4*)b3)[0], bb1 = ((const float4*)b3)[1];
    float4 w0 = ((const float4*)Wf)[0],  w1 = ((const float4*)Wf)[1];
    float4 r0v = f4relu(di, a0, bb0);
    float4 r1v = f4relu(di, a1, bb1);
    float s = bf[0];
    s += r0v.x * w0.x + r0v.y * w0.y + r0v.z * w0.z + r0v.w * w0.w;
    s += r1v.x * w1.x + r1v.y * w1.y + r1v.z * w1.z + r1v.w * w1.w;
    out[i] = s;
}

// ---------------- launch ----------------

extern "C" void kernel_launch(void* const* d_in, const int* in_sizes, int n_in,
                              void* d_out, int out_size, void* d_ws, size_t ws_size,
                              hipStream_t stream) {
    const float* x  = (const float*)d_in[0];
    const int*   ei = (const int*)d_in[1];
    const float* W1 = (const float*)d_in[2];
    const float* b1 = (const float*)d_in[3];
    const float* W2 = (const float*)d_in[4];
    const float* b2 = (const float*)d_in[5];
    const float* W3 = (const float*)d_in[6];
    const float* b3 = (const float*)d_in[7];
    const float* Wf = (const float*)d_in[8];
    const float* bf = (const float*)d_in[9];
    float* out = (float*)d_out;

    const int n = N_NODES;
    const int e = N_EDGES;
    const int* src = ei;
    const int* dst = ei + e;

    // workspace: xd[n]f4 | h2n[n*4]f4 | h3n[n*2]f4 | dinv[n] |
    //            srcs[NREG*CAP] | staging[NREG*CAP] | rowptr[n] | rowend[n] | regionCursor[NREG]
    float4*   xd   = (float4*)d_ws;
    float4*   h2n  = xd + n;
    float4*   h3n  = h2n + (size_t)n * 4;
    float*    dinv = (float*)(h3n + (size_t)n * 2);
    int*      srcs    = (int*)(dinv + n);
    unsigned* staging = (unsigned*)(srcs + (size_t)NREG * CAP);
    int*      rowptr  = (int*)(staging + (size_t)NREG * CAP);
    int*      rowend  = rowptr + n;
    int*      regionCursor = rowend + n;

    const int B = 256;

    // ---- CSR build (single-pass radix partition) ----
    k_zero_cur<<<1, 256, 0, stream>>>(regionCursor);
    k_place<<<NWG_E, B, 0, stream>>>(src, dst, regionCursor, staging);
    k_build<<<NREG, 512, 0, stream>>>(staging, regionCursor, x, rowptr, rowend, dinv, xd, srcs);

    // ---- fused layers ----
    g1k12<<<cdiv(n, B), B, 0, stream>>>(rowptr, rowend, srcs, xd, dinv, b1, W1, W2, h2n, n);
    g2<<<cdiv(n, B), B, 0, stream>>>(rowptr, rowend, srcs, h2n, dinv, b2, W3, h3n, n);
    g3<<<cdiv(n, B), B, 0, stream>>>(rowptr, rowend, srcs, h3n, dinv, b3, Wf, bf, out, n);
}